// Round 9
// baseline (290.371 us; speedup 1.0000x reference)
//
#include <hip/hip_runtime.h>
#include <hip/hip_fp16.h>
#include <math.h>

// MSMOM: multi-scale soft morphological opening + BN/ReLU + 1x1 conv + BN/ReLU
// B=4, C=64, H=W=256, k=3, dilations 1..4, beta=15.
//
// Morph computed in exp2-domain: soft-ero/dil are linear correlations on
// P = 2^{-K x} (K = beta*log2e).  S1 = sum W*P  ->  2^{K e} = 1/S1 (rcp);
// dilation: out = C1*log2( sum Wd * (1/S1) ).  No per-pixel max needed.
//
// History notes (keep):
//  - pk-FMA in morph RETIRED (r5: VGPR 68->172, 30x regression).
//  - conv schedule experiments (r4-r8: barriers / barrier-free / fences /
//    ring-3 global_load_lds counted-vmcnt) ALL NEUTRAL at ~105-130 us.
//    Session-wide max observed HBM BW = ~1.85 TB/s on every kernel ->
//    both kernels are at this allocation's BW roofline, and the 256-MiB
//    working set (x + cat + out) == L3 size -> cat thrashes out of L3.
//  - r9: slice the pipeline per batch (morph(b); conv(b)) so conv reads a
//    32-MiB cat slice still L3-resident.  Kernel bodies identical to r8.

constexpr int C_ = 64, H_ = 256, W_ = 256;
constexpr int HW = H_ * W_;
constexpr float EPSV = 1e-5f;
constexpr float KL2E = 21.64042561333445f;    // beta * log2(e)
constexpr float C1   = 0.046209812037329684f; // ln(2) / beta

typedef __attribute__((ext_vector_type(8))) _Float16 half8v;
typedef __attribute__((ext_vector_type(4))) _Float16 half4v;
typedef __attribute__((ext_vector_type(4))) float f32x4;
typedef __attribute__((ext_vector_type(2))) float f32x2;

typedef const __attribute__((address_space(1))) void gvoid;
typedef __attribute__((address_space(3))) void svoid;

__device__ _Float16 g_wh[64 * 256];  // conv weights fp16, row-major [o][c]
__device__ float g_scale[64];
__device__ float g_shift[64];
__device__ float g_we9e[4 * 64 * 9]; // 2^{K*we}
__device__ float g_wd9e[4 * 64 * 9]; // 2^{K*wd}
__device__ float g_cs[4 * 64];       // C1 * bn_scale  (per d,c)
__device__ float g_sh[4 * 64];       // bn shift       (per d,c)

__global__ __launch_bounds__(256) void prep(
    const float* __restrict__ cw, const float* __restrict__ g,
    const float* __restrict__ bb, const float* __restrict__ bm,
    const float* __restrict__ bv, const float* __restrict__ we,
    const float* __restrict__ wd, const float* __restrict__ bng,
    const float* __restrict__ bnb, const float* __restrict__ bnm,
    const float* __restrict__ bnv)
{
    int i = blockIdx.x * 256 + threadIdx.x;  // 16384 total
    g_wh[i] = (_Float16)cw[i];
    if (i < 64) {
        float s = g[i] * rsqrtf(bv[i] + EPSV);
        g_scale[i] = s;
        g_shift[i] = bb[i] - bm[i] * s;
    }
    if (i < 2304) {
        g_we9e[i] = __builtin_amdgcn_exp2f(KL2E * we[i]);
        g_wd9e[i] = __builtin_amdgcn_exp2f(KL2E * wd[i]);
    }
    if (i < 256) {
        float s = bng[i] * rsqrtf(bnv[i] + EPSV);
        g_cs[i] = C1 * s;
        g_sh[i] = bnb[i] - bnm[i] * s;
    }
}

// PROVEN round-1 morph body (VGPR 68) — only change: batch from kernel arg
// (grid sliced per batch for L3 locality of the cat slice).
__global__ __launch_bounds__(256) void morph_all(
    const float* __restrict__ x, _Float16* __restrict__ cat, const int b)
{
    __shared__ __align__(16) float xs[80 * 92];
    __shared__ __align__(16) float es[72 * 76];
    const int tid = threadIdx.x;
    const int tileW = blockIdx.x & 3, tileH = blockIdx.x >> 2;  // 4x4 tiles
    const int c = blockIdx.y;
    const int h0 = tileH * 64, w0 = tileW * 64;
    const float* xc = x + (b * C_ + c) * HW;

    for (int u = tid; u < 1600; u += 256) {
        int r = u / 20, q4 = (u - r * 20) * 4;
        int gh = h0 - 8 + r, gw = w0 - 8 + q4;
        int ch = min(max(gh, 0), 255), cwi = min(max(gw, 0), 252);
        const float4 v = *(const float4*)&xc[ch * W_ + cwi];
        bool ok = ((unsigned)gh < 256u) && ((unsigned)gw < 253u);
        float4 sv;
        sv.x = ok ? __builtin_amdgcn_exp2f(-KL2E * v.x) : 0.f;
        sv.y = ok ? __builtin_amdgcn_exp2f(-KL2E * v.y) : 0.f;
        sv.z = ok ? __builtin_amdgcn_exp2f(-KL2E * v.z) : 0.f;
        sv.w = ok ? __builtin_amdgcn_exp2f(-KL2E * v.w) : 0.f;
        *(float4*)&xs[r * 92 + q4] = sv;
    }

    #pragma unroll
    for (int d = 0; d < 4; d++) {
        const int D = d + 1;
        const int bc = d * C_ + c;

        float w9[9], wd9[9];
        #pragma unroll
        for (int i = 0; i < 9; i++) {
            w9[i]  = g_we9e[bc * 9 + i];
            wd9[i] = g_wd9e[bc * 9 + i];
        }
        const float cs = g_cs[bc];
        const float shift = g_sh[bc];

        __syncthreads();

        for (int g = tid; g < 360; g += 256) {
            const int col = g / 72;
            const int row = g - col * 72;
            const int qa0 = col * 16;
            float s16[16];
            #pragma unroll
            for (int p = 0; p < 16; p++) s16[p] = 0.f;
            #pragma unroll
            for (int i = 0; i < 3; i++) {
                const f32x4* xr = (const f32x4*)&xs[(row + 4 + (i - 1) * D) * 92 + qa0];
                f32x4 xw[6];
                #pragma unroll
                for (int k = 0; k < 6; k++) xw[k] = xr[k];
                #pragma unroll
                for (int j = 0; j < 3; j++) {
                    const float wv = w9[i * 3 + j];
                    #pragma unroll
                    for (int p = 0; p < 16; p++) {
                        const int wi = (4 - D) + p + j * D;
                        s16[p] = fmaf(wv, xw[wi >> 2][wi & 3], s16[p]);
                    }
                }
            }
            const bool rowok = (unsigned)(h0 + row - 4) < 256u;
            const int gw0 = w0 + qa0 - 4;
            f32x4 ev[4];
            #pragma unroll
            for (int p = 0; p < 16; p++) {
                float gv = __builtin_amdgcn_rcpf(fmaxf(s16[p], 1e-38f));
                bool ok = rowok && ((unsigned)(gw0 + p) < 256u);
                ev[p >> 2][p & 3] = ok ? gv : 0.f;
            }
            f32x4* ep = (f32x4*)&es[row * 76 + qa0];
            ep[0] = ev[0]; ep[1] = ev[1];
            if (qa0 < 64) { ep[2] = ev[2]; ep[3] = ev[3]; }
        }

        __syncthreads();

        {
            const int dr = tid >> 2, dq0 = (tid & 3) * 16;
            float s16[16];
            #pragma unroll
            for (int p = 0; p < 16; p++) s16[p] = 0.f;
            #pragma unroll
            for (int i = 0; i < 3; i++) {
                const f32x4* er = (const f32x4*)&es[(dr + 4 + (i - 1) * D) * 76 + dq0];
                f32x4 ew[6];
                #pragma unroll
                for (int k = 0; k < 6; k++) ew[k] = er[k];
                #pragma unroll
                for (int j = 0; j < 3; j++) {
                    const float wv = wd9[i * 3 + j];
                    #pragma unroll
                    for (int p = 0; p < 16; p++) {
                        const int wi = (4 - D) + p + j * D;
                        s16[p] = fmaf(wv, ew[wi >> 2][wi & 3], s16[p]);
                    }
                }
            }
            half8v hv0, hv1;
            #pragma unroll
            for (int p = 0; p < 16; p++) {
                float y = __builtin_amdgcn_logf(fmaxf(s16[p], 1e-38f)) * cs + shift;
                y = fmaxf(0.f, y);
                if (p < 8) hv0[p] = (_Float16)y; else hv1[p - 8] = (_Float16)y;
            }
            _Float16* cp = &cat[((size_t)((b * 4 + d) * C_ + c)) * HW
                                + (h0 + dr) * W_ + (w0 + dq0)];
            *(half8v*)cp = hv0;
            *(half8v*)(cp + 8) = hv1;
        }
    }
}

// Out[64 x 65536] = W[64x256] * Cat[256x65536] per batch, mfma_f32_16x16x32_f16.
// r8-proven body (ring-3 global_load_lds, counted vmcnt, barrier-free,
// tr-read subtiles); only change: batch from kernel arg (grid (256,1)).
__global__ __launch_bounds__(256) void conv_mfma(
    const _Float16* __restrict__ cat, float* __restrict__ out, const int b)
{
    __shared__ __align__(16) _Float16 T[3][4][2048];  // 49,152 B
    const int tid = threadIdx.x;
    const int lane = tid & 63, wave = tid >> 6;
    const int m = lane & 15, quad = lane >> 4;
    const int px0 = blockIdx.x * 256;
    const _Float16* catb = cat + (size_t)b * 256 * HW + px0;

    // staging decode (per-lane global src; dest is lane-linear by HW)
    const int c4sel = lane >> 5, p16s = (lane >> 3) & 3;
    const int chl = (lane >> 1) & 3, halfs = lane & 1;
    const int ch_in_q = c4sel * 4 + chl;                 // 0..7
    const int px_s = wave * 64 + p16s * 16 + halfs * 8;  // lane's src px base

    const uint t0a = (uint)(uintptr_t)&T[0][0][0];
    const uint trlane = (uint)(quad * 1024 + m * 8);

    f32x4 acc[4][4];
    #pragma unroll
    for (int ot = 0; ot < 4; ot++)
        #pragma unroll
        for (int pt = 0; pt < 4; pt++)
            acc[ot][pt] = (f32x4){0.f, 0.f, 0.f, 0.f};

    half8v a[3][4];

    auto STAGE = [&](int kcs) {
        #pragma unroll
        for (int q = 0; q < 4; ++q) {
            const _Float16* gp = catb + (size_t)(kcs * 32 + q * 8 + ch_in_q) * HW + px_s;
            __builtin_amdgcn_global_load_lds(
                (gvoid*)gp, (svoid*)&T[kcs % 3][wave][q * 512], 16, 0, 0);
        }
    };
    auto LOADA = [&](int kcs) {
        #pragma unroll
        for (int i = 0; i < 4; ++i)
            a[kcs % 3][i] = *(const half8v*)&g_wh[(i * 16 + m) * 256 + kcs * 32 + quad * 8];
    };

    // prologue (FIFO: S0,A0,S1,A1,S2) — sched_barriers pin issue order
    STAGE(0); __builtin_amdgcn_sched_barrier(0);
    LOADA(0); __builtin_amdgcn_sched_barrier(0);
    STAGE(1); __builtin_amdgcn_sched_barrier(0);
    LOADA(1); __builtin_amdgcn_sched_barrier(0);
    STAGE(2); __builtin_amdgcn_sched_barrier(0);

    #pragma unroll
    for (int kc = 0; kc < 8; ++kc) {
        // counted wait: S(kc)+A(kc) complete, deeper stages stay in flight
        if (kc < 6)       asm volatile("s_waitcnt vmcnt(12)");
        else if (kc == 6) asm volatile("s_waitcnt vmcnt(8)");
        else              asm volatile("s_waitcnt vmcnt(0)");
        __builtin_amdgcn_sched_barrier(0);

        const uint wb = t0a + (uint)(((kc % 3) * 4 + wave) * 4096) + trlane;
        f32x2 trd[4][2];
        #pragma unroll
        for (int pt = 0; pt < 4; ++pt) {
            asm volatile("ds_read_b64_tr_b16 %0, %1"
                         : "=v"(trd[pt][0]) : "v"(wb + pt * 128));
            asm volatile("ds_read_b64_tr_b16 %0, %1"
                         : "=v"(trd[pt][1]) : "v"(wb + 512 + pt * 128));
        }
        asm volatile("s_waitcnt lgkmcnt(0)");
        __builtin_amdgcn_sched_barrier(0);  // rule 18: MFMAs stay below the wait

        #pragma unroll
        for (int pt = 0; pt < 4; ++pt) {
            half4v lo = __builtin_bit_cast(half4v, trd[pt][0]);
            half4v hi = __builtin_bit_cast(half4v, trd[pt][1]);
            half8v bf = __builtin_shufflevector(lo, hi, 0, 1, 2, 3, 4, 5, 6, 7);
            acc[0][pt] = __builtin_amdgcn_mfma_f32_16x16x32_f16(a[kc % 3][0], bf, acc[0][pt], 0, 0, 0);
            acc[1][pt] = __builtin_amdgcn_mfma_f32_16x16x32_f16(a[kc % 3][1], bf, acc[1][pt], 0, 0, 0);
            acc[2][pt] = __builtin_amdgcn_mfma_f32_16x16x32_f16(a[kc % 3][2], bf, acc[2][pt], 0, 0, 0);
            acc[3][pt] = __builtin_amdgcn_mfma_f32_16x16x32_f16(a[kc % 3][3], bf, acc[3][pt], 0, 0, 0);
        }
        __builtin_amdgcn_sched_barrier(0);

        if (kc < 6) { LOADA(kc + 2); }          // A depth 2
        __builtin_amdgcn_sched_barrier(0);
        if (kc < 5) { STAGE(kc + 3); }          // stage depth 3, ring-3
        __builtin_amdgcn_sched_barrier(0);
    }

    // D layout: row(o) = quad*4 + reg, col(px) = m
    #pragma unroll
    for (int ot = 0; ot < 4; ot++)
        #pragma unroll
        for (int reg = 0; reg < 4; reg++) {
            const int o = ot * 16 + quad * 4 + reg;
            const float sc = g_scale[o], sh = g_shift[o];
            float* ob = out + ((size_t)(b * 64 + o)) * HW + px0;
            #pragma unroll
            for (int pt = 0; pt < 4; pt++) {
                const int pxl = wave * 64 + pt * 16 + m;
                ob[pxl] = fmaxf(0.f, acc[ot][pt][reg] * sc + sh);
            }
        }
}

extern "C" void kernel_launch(void* const* d_in, const int* in_sizes, int n_in,
                              void* d_out, int out_size, void* d_ws, size_t ws_size,
                              hipStream_t stream)
{
    const float* x   = (const float*)d_in[0];
    const float* we  = (const float*)d_in[1];
    const float* wd  = (const float*)d_in[2];
    const float* bng = (const float*)d_in[3];
    const float* bnb = (const float*)d_in[4];
    const float* bnm = (const float*)d_in[5];
    const float* bnv = (const float*)d_in[6];
    const float* cw  = (const float*)d_in[7];
    const float* fg  = (const float*)d_in[8];
    const float* fb  = (const float*)d_in[9];
    const float* fm  = (const float*)d_in[10];
    const float* fv  = (const float*)d_in[11];
    float* out = (float*)d_out;
    _Float16* cat = (_Float16*)d_ws;  // 4*256*65536*2 B = 128 MiB

    prep<<<64, 256, 0, stream>>>(cw, fg, fb, fm, fv, we, wd, bng, bnb, bnm, bnv);
    // Per-batch pipeline: conv(b) reads the 32-MiB cat slice morph(b) just
    // wrote -> slice stays L3-resident (64-MiB phase working set vs 256-MiB
    // all-at-once, which thrashed).  Kernel bodies unchanged from r8.
    for (int b = 0; b < 4; ++b) {
        morph_all<<<dim3(16, 64, 1), 256, 0, stream>>>(x, cat, b);
        conv_mfma<<<dim3(256, 1, 1), 256, 0, stream>>>(cat, out, b);
    }
}

// Round 10
// 246.606 us; speedup vs baseline: 1.1775x; 1.1775x over previous
//
#include <hip/hip_runtime.h>
#include <hip/hip_fp16.h>
#include <math.h>

// MSMOM: multi-scale soft morphological opening + BN/ReLU + 1x1 conv + BN/ReLU
// B=4, C=64, H=W=256, k=3, dilations 1..4, beta=15.
//
// Morph computed in exp2-domain: soft-ero/dil are linear correlations on
// P = 2^{-K x} (K = beta*log2e).  S1 = sum W*P  ->  2^{K e} = 1/S1 (rcp);
// dilation: out = C1*log2( sum Wd * (1/S1) ).  No per-pixel max needed.
//
// History notes (keep):
//  - pk-FMA in morph RETIRED (r5: VGPR 68->172, 30x regression).
//  - conv schedule experiments (r4-r8) ALL NEUTRAL at ~105-130 us.
//  - r9 per-batch slicing REGRESSED (290): launch overhead + 1 block/CU conv.
//    But r9 profile showed fillBuffer at 6.5 TB/s -> the "1.85 TB/s machine
//    cap" theory is DEAD.  Remaining explanation for conv's schedule-
//    insensitive 1.8 TB/s: its fetch = 256 streams at exactly 128-KiB
//    stride (channel rows) -> DRAM bank / L2-set aliasing.
//  - r10: cat layout swapped to [b][h][ch][w].  A conv block (one h row)
//    reads ONE contiguous 128-KiB panel; each stage instruction touches a
//    single DRAM page.  Morph write rows scatter instead (writes drain
//    lazily via L2; morph is VALU-bound).  Kernel bodies = proven r8.

constexpr int C_ = 64, H_ = 256, W_ = 256;
constexpr int HW = H_ * W_;
constexpr float EPSV = 1e-5f;
constexpr float KL2E = 21.64042561333445f;    // beta * log2(e)
constexpr float C1   = 0.046209812037329684f; // ln(2) / beta

typedef __attribute__((ext_vector_type(8))) _Float16 half8v;
typedef __attribute__((ext_vector_type(4))) _Float16 half4v;
typedef __attribute__((ext_vector_type(4))) float f32x4;
typedef __attribute__((ext_vector_type(2))) float f32x2;

typedef const __attribute__((address_space(1))) void gvoid;
typedef __attribute__((address_space(3))) void svoid;

__device__ _Float16 g_wh[64 * 256];  // conv weights fp16, row-major [o][c]
__device__ float g_scale[64];
__device__ float g_shift[64];
__device__ float g_we9e[4 * 64 * 9]; // 2^{K*we}
__device__ float g_wd9e[4 * 64 * 9]; // 2^{K*wd}
__device__ float g_cs[4 * 64];       // C1 * bn_scale  (per d,c)
__device__ float g_sh[4 * 64];       // bn shift       (per d,c)

__global__ __launch_bounds__(256) void prep(
    const float* __restrict__ cw, const float* __restrict__ g,
    const float* __restrict__ bb, const float* __restrict__ bm,
    const float* __restrict__ bv, const float* __restrict__ we,
    const float* __restrict__ wd, const float* __restrict__ bng,
    const float* __restrict__ bnb, const float* __restrict__ bnm,
    const float* __restrict__ bnv)
{
    int i = blockIdx.x * 256 + threadIdx.x;  // 16384 total
    g_wh[i] = (_Float16)cw[i];
    if (i < 64) {
        float s = g[i] * rsqrtf(bv[i] + EPSV);
        g_scale[i] = s;
        g_shift[i] = bb[i] - bm[i] * s;
    }
    if (i < 2304) {
        g_we9e[i] = __builtin_amdgcn_exp2f(KL2E * we[i]);
        g_wd9e[i] = __builtin_amdgcn_exp2f(KL2E * wd[i]);
    }
    if (i < 256) {
        float s = bng[i] * rsqrtf(bnv[i] + EPSV);
        g_cs[i] = C1 * s;
        g_sh[i] = bnb[i] - bnm[i] * s;
    }
}

// PROVEN round-1 morph body (113 us, VGPR 68).  Only change vs r8: the cat
// store address uses the [b][h][ch][w] layout (ch = d*64+c).
__global__ __launch_bounds__(256) void morph_all(
    const float* __restrict__ x, _Float16* __restrict__ cat)
{
    __shared__ __align__(16) float xs[80 * 92];
    __shared__ __align__(16) float es[72 * 76];
    const int tid = threadIdx.x;
    const int tileW = blockIdx.x & 3, tileH = blockIdx.x >> 2;  // 4x4 tiles
    const int c = blockIdx.y, b = blockIdx.z;
    const int h0 = tileH * 64, w0 = tileW * 64;
    const float* xc = x + (b * C_ + c) * HW;

    for (int u = tid; u < 1600; u += 256) {
        int r = u / 20, q4 = (u - r * 20) * 4;
        int gh = h0 - 8 + r, gw = w0 - 8 + q4;
        int ch = min(max(gh, 0), 255), cwi = min(max(gw, 0), 252);
        const float4 v = *(const float4*)&xc[ch * W_ + cwi];
        bool ok = ((unsigned)gh < 256u) && ((unsigned)gw < 253u);
        float4 sv;
        sv.x = ok ? __builtin_amdgcn_exp2f(-KL2E * v.x) : 0.f;
        sv.y = ok ? __builtin_amdgcn_exp2f(-KL2E * v.y) : 0.f;
        sv.z = ok ? __builtin_amdgcn_exp2f(-KL2E * v.z) : 0.f;
        sv.w = ok ? __builtin_amdgcn_exp2f(-KL2E * v.w) : 0.f;
        *(float4*)&xs[r * 92 + q4] = sv;
    }

    #pragma unroll
    for (int d = 0; d < 4; d++) {
        const int D = d + 1;
        const int bc = d * C_ + c;

        float w9[9], wd9[9];
        #pragma unroll
        for (int i = 0; i < 9; i++) {
            w9[i]  = g_we9e[bc * 9 + i];
            wd9[i] = g_wd9e[bc * 9 + i];
        }
        const float cs = g_cs[bc];
        const float shift = g_sh[bc];

        __syncthreads();

        for (int g = tid; g < 360; g += 256) {
            const int col = g / 72;
            const int row = g - col * 72;
            const int qa0 = col * 16;
            float s16[16];
            #pragma unroll
            for (int p = 0; p < 16; p++) s16[p] = 0.f;
            #pragma unroll
            for (int i = 0; i < 3; i++) {
                const f32x4* xr = (const f32x4*)&xs[(row + 4 + (i - 1) * D) * 92 + qa0];
                f32x4 xw[6];
                #pragma unroll
                for (int k = 0; k < 6; k++) xw[k] = xr[k];
                #pragma unroll
                for (int j = 0; j < 3; j++) {
                    const float wv = w9[i * 3 + j];
                    #pragma unroll
                    for (int p = 0; p < 16; p++) {
                        const int wi = (4 - D) + p + j * D;
                        s16[p] = fmaf(wv, xw[wi >> 2][wi & 3], s16[p]);
                    }
                }
            }
            const bool rowok = (unsigned)(h0 + row - 4) < 256u;
            const int gw0 = w0 + qa0 - 4;
            f32x4 ev[4];
            #pragma unroll
            for (int p = 0; p < 16; p++) {
                float gv = __builtin_amdgcn_rcpf(fmaxf(s16[p], 1e-38f));
                bool ok = rowok && ((unsigned)(gw0 + p) < 256u);
                ev[p >> 2][p & 3] = ok ? gv : 0.f;
            }
            f32x4* ep = (f32x4*)&es[row * 76 + qa0];
            ep[0] = ev[0]; ep[1] = ev[1];
            if (qa0 < 64) { ep[2] = ev[2]; ep[3] = ev[3]; }
        }

        __syncthreads();

        {
            const int dr = tid >> 2, dq0 = (tid & 3) * 16;
            float s16[16];
            #pragma unroll
            for (int p = 0; p < 16; p++) s16[p] = 0.f;
            #pragma unroll
            for (int i = 0; i < 3; i++) {
                const f32x4* er = (const f32x4*)&es[(dr + 4 + (i - 1) * D) * 76 + dq0];
                f32x4 ew[6];
                #pragma unroll
                for (int k = 0; k < 6; k++) ew[k] = er[k];
                #pragma unroll
                for (int j = 0; j < 3; j++) {
                    const float wv = wd9[i * 3 + j];
                    #pragma unroll
                    for (int p = 0; p < 16; p++) {
                        const int wi = (4 - D) + p + j * D;
                        s16[p] = fmaf(wv, ew[wi >> 2][wi & 3], s16[p]);
                    }
                }
            }
            half8v hv0, hv1;
            #pragma unroll
            for (int p = 0; p < 16; p++) {
                float y = __builtin_amdgcn_logf(fmaxf(s16[p], 1e-38f)) * cs + shift;
                y = fmaxf(0.f, y);
                if (p < 8) hv0[p] = (_Float16)y; else hv1[p - 8] = (_Float16)y;
            }
            // cat layout [b][h][ch][w], ch = d*64+c  (conv-friendly panels)
            _Float16* cp = &cat[(((size_t)(b * 256 + h0 + dr)) * 256
                                 + (d * C_ + c)) * 256 + (w0 + dq0)];
            *(half8v*)cp = hv0;
            *(half8v*)(cp + 8) = hv1;
        }
    }
}

// Out[64 x 65536] = W[64x256] * Cat per batch, mfma_f32_16x16x32_f16.
// r8-proven body (ring-3 global_load_lds, counted vmcnt, barrier-free,
// tr-read subtiles).  Only change: cat base/src arithmetic for the
// [b][h][ch][w] layout — block = one h row, K-panel is 128 KiB CONTIGUOUS.
__global__ __launch_bounds__(256) void conv_mfma(
    const _Float16* __restrict__ cat, float* __restrict__ out)
{
    __shared__ __align__(16) _Float16 T[3][4][2048];  // 49,152 B
    const int tid = threadIdx.x;
    const int lane = tid & 63, wave = tid >> 6;
    const int m = lane & 15, quad = lane >> 4;
    const int b = blockIdx.y;
    const int h = blockIdx.x;                 // one image row per block
    const int px0 = h * 256;
    const _Float16* catb = cat + ((size_t)(b * 256 + h)) * 256 * 256;  // [ch][w]

    // staging decode (per-lane global src; dest is lane-linear by HW)
    const int c4sel = lane >> 5, p16s = (lane >> 3) & 3;
    const int chl = (lane >> 1) & 3, halfs = lane & 1;
    const int ch_in_q = c4sel * 4 + chl;                 // 0..7
    const int px_s = wave * 64 + p16s * 16 + halfs * 8;  // lane's w base

    const uint t0a = (uint)(uintptr_t)&T[0][0][0];
    const uint trlane = (uint)(quad * 1024 + m * 8);

    f32x4 acc[4][4];
    #pragma unroll
    for (int ot = 0; ot < 4; ot++)
        #pragma unroll
        for (int pt = 0; pt < 4; pt++)
            acc[ot][pt] = (f32x4){0.f, 0.f, 0.f, 0.f};

    half8v a[3][4];

    auto STAGE = [&](int kcs) {
        #pragma unroll
        for (int q = 0; q < 4; ++q) {
            const _Float16* gp = catb + (size_t)(kcs * 32 + q * 8 + ch_in_q) * 256 + px_s;
            __builtin_amdgcn_global_load_lds(
                (gvoid*)gp, (svoid*)&T[kcs % 3][wave][q * 512], 16, 0, 0);
        }
    };
    auto LOADA = [&](int kcs) {
        #pragma unroll
        for (int i = 0; i < 4; ++i)
            a[kcs % 3][i] = *(const half8v*)&g_wh[(i * 16 + m) * 256 + kcs * 32 + quad * 8];
    };

    // prologue (FIFO: S0,A0,S1,A1,S2) — sched_barriers pin issue order
    STAGE(0); __builtin_amdgcn_sched_barrier(0);
    LOADA(0); __builtin_amdgcn_sched_barrier(0);
    STAGE(1); __builtin_amdgcn_sched_barrier(0);
    LOADA(1); __builtin_amdgcn_sched_barrier(0);
    STAGE(2); __builtin_amdgcn_sched_barrier(0);

    #pragma unroll
    for (int kc = 0; kc < 8; ++kc) {
        // counted wait: S(kc)+A(kc) complete, deeper stages stay in flight
        if (kc < 6)       asm volatile("s_waitcnt vmcnt(12)");
        else if (kc == 6) asm volatile("s_waitcnt vmcnt(8)");
        else              asm volatile("s_waitcnt vmcnt(0)");
        __builtin_amdgcn_sched_barrier(0);

        const uint wb = t0a + (uint)(((kc % 3) * 4 + wave) * 4096) + trlane;
        f32x2 trd[4][2];
        #pragma unroll
        for (int pt = 0; pt < 4; ++pt) {
            asm volatile("ds_read_b64_tr_b16 %0, %1"
                         : "=v"(trd[pt][0]) : "v"(wb + pt * 128));
            asm volatile("ds_read_b64_tr_b16 %0, %1"
                         : "=v"(trd[pt][1]) : "v"(wb + 512 + pt * 128));
        }
        asm volatile("s_waitcnt lgkmcnt(0)");
        __builtin_amdgcn_sched_barrier(0);  // rule 18: MFMAs stay below the wait

        #pragma unroll
        for (int pt = 0; pt < 4; ++pt) {
            half4v lo = __builtin_bit_cast(half4v, trd[pt][0]);
            half4v hi = __builtin_bit_cast(half4v, trd[pt][1]);
            half8v bf = __builtin_shufflevector(lo, hi, 0, 1, 2, 3, 4, 5, 6, 7);
            acc[0][pt] = __builtin_amdgcn_mfma_f32_16x16x32_f16(a[kc % 3][0], bf, acc[0][pt], 0, 0, 0);
            acc[1][pt] = __builtin_amdgcn_mfma_f32_16x16x32_f16(a[kc % 3][1], bf, acc[1][pt], 0, 0, 0);
            acc[2][pt] = __builtin_amdgcn_mfma_f32_16x16x32_f16(a[kc % 3][2], bf, acc[2][pt], 0, 0, 0);
            acc[3][pt] = __builtin_amdgcn_mfma_f32_16x16x32_f16(a[kc % 3][3], bf, acc[3][pt], 0, 0, 0);
        }
        __builtin_amdgcn_sched_barrier(0);

        if (kc < 6) { LOADA(kc + 2); }          // A depth 2
        __builtin_amdgcn_sched_barrier(0);
        if (kc < 5) { STAGE(kc + 3); }          // stage depth 3, ring-3
        __builtin_amdgcn_sched_barrier(0);
    }

    // D layout: row(o) = quad*4 + reg, col(px) = m
    #pragma unroll
    for (int ot = 0; ot < 4; ot++)
        #pragma unroll
        for (int reg = 0; reg < 4; reg++) {
            const int o = ot * 16 + quad * 4 + reg;
            const float sc = g_scale[o], sh = g_shift[o];
            float* ob = out + ((size_t)(b * 64 + o)) * HW + px0;
            #pragma unroll
            for (int pt = 0; pt < 4; pt++) {
                const int pxl = wave * 64 + pt * 16 + m;
                ob[pxl] = fmaxf(0.f, acc[ot][pt][reg] * sc + sh);
            }
        }
}

extern "C" void kernel_launch(void* const* d_in, const int* in_sizes, int n_in,
                              void* d_out, int out_size, void* d_ws, size_t ws_size,
                              hipStream_t stream)
{
    const float* x   = (const float*)d_in[0];
    const float* we  = (const float*)d_in[1];
    const float* wd  = (const float*)d_in[2];
    const float* bng = (const float*)d_in[3];
    const float* bnb = (const float*)d_in[4];
    const float* bnm = (const float*)d_in[5];
    const float* bnv = (const float*)d_in[6];
    const float* cw  = (const float*)d_in[7];
    const float* fg  = (const float*)d_in[8];
    const float* fb  = (const float*)d_in[9];
    const float* fm  = (const float*)d_in[10];
    const float* fv  = (const float*)d_in[11];
    float* out = (float*)d_out;
    _Float16* cat = (_Float16*)d_ws;  // [b][h][ch][w] fp16 = 128 MiB

    prep<<<64, 256, 0, stream>>>(cw, fg, fb, fm, fv, we, wd, bng, bnb, bnm, bnv);
    morph_all<<<dim3(16, 64, 4), 256, 0, stream>>>(x, cat);
    conv_mfma<<<dim3(256, 4), 256, 0, stream>>>(cat, out);
}

// Round 11
// 245.203 us; speedup vs baseline: 1.1842x; 1.0057x over previous
//
#include <hip/hip_runtime.h>
#include <hip/hip_fp16.h>
#include <math.h>

// MSMOM: multi-scale soft morphological opening + BN/ReLU + 1x1 conv + BN/ReLU
// B=4, C=64, H=W=256, k=3, dilations 1..4, beta=15.
//
// Morph computed in exp2-domain: soft-ero/dil are linear correlations on
// P = 2^{-K x} (K = beta*log2e).  S1 = sum W*P  ->  2^{K e} = 1/S1 (rcp);
// dilation: out = C1*log2( sum Wd * (1/S1) ).  No per-pixel max needed.
//
// History notes (keep):
//  - pk-FMA in morph RETIRED (r5: VGPR 68->172, 30x regression).
//  - conv READ-side experiments ALL NEUTRAL (r4-r10): barriers/fences/
//    reg-vs-LDS staging/ring-3 counted vmcnt/channel-strided vs contiguous
//    cat panels.  Non-morph residual = 133+-3 us across ALL variants.
//  - The one shared untouched element: the epilogue's 64 scalar
//    global_store_dword per thread (4x64-B segments, 256-KiB row stride).
//    r11: LDS-bounce epilogue -> 16x f32x4 stores, 1-KiB contiguous per
//    wave-instruction.  Everything upstream byte-identical to r10.

constexpr int C_ = 64, H_ = 256, W_ = 256;
constexpr int HW = H_ * W_;
constexpr float EPSV = 1e-5f;
constexpr float KL2E = 21.64042561333445f;    // beta * log2(e)
constexpr float C1   = 0.046209812037329684f; // ln(2) / beta

typedef __attribute__((ext_vector_type(8))) _Float16 half8v;
typedef __attribute__((ext_vector_type(4))) _Float16 half4v;
typedef __attribute__((ext_vector_type(4))) float f32x4;
typedef __attribute__((ext_vector_type(2))) float f32x2;

typedef const __attribute__((address_space(1))) void gvoid;
typedef __attribute__((address_space(3))) void svoid;

__device__ _Float16 g_wh[64 * 256];  // conv weights fp16, row-major [o][c]
__device__ float g_scale[64];
__device__ float g_shift[64];
__device__ float g_we9e[4 * 64 * 9]; // 2^{K*we}
__device__ float g_wd9e[4 * 64 * 9]; // 2^{K*wd}
__device__ float g_cs[4 * 64];       // C1 * bn_scale  (per d,c)
__device__ float g_sh[4 * 64];       // bn shift       (per d,c)

__global__ __launch_bounds__(256) void prep(
    const float* __restrict__ cw, const float* __restrict__ g,
    const float* __restrict__ bb, const float* __restrict__ bm,
    const float* __restrict__ bv, const float* __restrict__ we,
    const float* __restrict__ wd, const float* __restrict__ bng,
    const float* __restrict__ bnb, const float* __restrict__ bnm,
    const float* __restrict__ bnv)
{
    int i = blockIdx.x * 256 + threadIdx.x;  // 16384 total
    g_wh[i] = (_Float16)cw[i];
    if (i < 64) {
        float s = g[i] * rsqrtf(bv[i] + EPSV);
        g_scale[i] = s;
        g_shift[i] = bb[i] - bm[i] * s;
    }
    if (i < 2304) {
        g_we9e[i] = __builtin_amdgcn_exp2f(KL2E * we[i]);
        g_wd9e[i] = __builtin_amdgcn_exp2f(KL2E * wd[i]);
    }
    if (i < 256) {
        float s = bng[i] * rsqrtf(bnv[i] + EPSV);
        g_cs[i] = C1 * s;
        g_sh[i] = bnb[i] - bnm[i] * s;
    }
}

// PROVEN round-1 morph body (113 us, VGPR 68); cat layout [b][h][ch][w]
// (r10, passing).  Unchanged this round.
__global__ __launch_bounds__(256) void morph_all(
    const float* __restrict__ x, _Float16* __restrict__ cat)
{
    __shared__ __align__(16) float xs[80 * 92];
    __shared__ __align__(16) float es[72 * 76];
    const int tid = threadIdx.x;
    const int tileW = blockIdx.x & 3, tileH = blockIdx.x >> 2;  // 4x4 tiles
    const int c = blockIdx.y, b = blockIdx.z;
    const int h0 = tileH * 64, w0 = tileW * 64;
    const float* xc = x + (b * C_ + c) * HW;

    for (int u = tid; u < 1600; u += 256) {
        int r = u / 20, q4 = (u - r * 20) * 4;
        int gh = h0 - 8 + r, gw = w0 - 8 + q4;
        int ch = min(max(gh, 0), 255), cwi = min(max(gw, 0), 252);
        const float4 v = *(const float4*)&xc[ch * W_ + cwi];
        bool ok = ((unsigned)gh < 256u) && ((unsigned)gw < 253u);
        float4 sv;
        sv.x = ok ? __builtin_amdgcn_exp2f(-KL2E * v.x) : 0.f;
        sv.y = ok ? __builtin_amdgcn_exp2f(-KL2E * v.y) : 0.f;
        sv.z = ok ? __builtin_amdgcn_exp2f(-KL2E * v.z) : 0.f;
        sv.w = ok ? __builtin_amdgcn_exp2f(-KL2E * v.w) : 0.f;
        *(float4*)&xs[r * 92 + q4] = sv;
    }

    #pragma unroll
    for (int d = 0; d < 4; d++) {
        const int D = d + 1;
        const int bc = d * C_ + c;

        float w9[9], wd9[9];
        #pragma unroll
        for (int i = 0; i < 9; i++) {
            w9[i]  = g_we9e[bc * 9 + i];
            wd9[i] = g_wd9e[bc * 9 + i];
        }
        const float cs = g_cs[bc];
        const float shift = g_sh[bc];

        __syncthreads();

        for (int g = tid; g < 360; g += 256) {
            const int col = g / 72;
            const int row = g - col * 72;
            const int qa0 = col * 16;
            float s16[16];
            #pragma unroll
            for (int p = 0; p < 16; p++) s16[p] = 0.f;
            #pragma unroll
            for (int i = 0; i < 3; i++) {
                const f32x4* xr = (const f32x4*)&xs[(row + 4 + (i - 1) * D) * 92 + qa0];
                f32x4 xw[6];
                #pragma unroll
                for (int k = 0; k < 6; k++) xw[k] = xr[k];
                #pragma unroll
                for (int j = 0; j < 3; j++) {
                    const float wv = w9[i * 3 + j];
                    #pragma unroll
                    for (int p = 0; p < 16; p++) {
                        const int wi = (4 - D) + p + j * D;
                        s16[p] = fmaf(wv, xw[wi >> 2][wi & 3], s16[p]);
                    }
                }
            }
            const bool rowok = (unsigned)(h0 + row - 4) < 256u;
            const int gw0 = w0 + qa0 - 4;
            f32x4 ev[4];
            #pragma unroll
            for (int p = 0; p < 16; p++) {
                float gv = __builtin_amdgcn_rcpf(fmaxf(s16[p], 1e-38f));
                bool ok = rowok && ((unsigned)(gw0 + p) < 256u);
                ev[p >> 2][p & 3] = ok ? gv : 0.f;
            }
            f32x4* ep = (f32x4*)&es[row * 76 + qa0];
            ep[0] = ev[0]; ep[1] = ev[1];
            if (qa0 < 64) { ep[2] = ev[2]; ep[3] = ev[3]; }
        }

        __syncthreads();

        {
            const int dr = tid >> 2, dq0 = (tid & 3) * 16;
            float s16[16];
            #pragma unroll
            for (int p = 0; p < 16; p++) s16[p] = 0.f;
            #pragma unroll
            for (int i = 0; i < 3; i++) {
                const f32x4* er = (const f32x4*)&es[(dr + 4 + (i - 1) * D) * 76 + dq0];
                f32x4 ew[6];
                #pragma unroll
                for (int k = 0; k < 6; k++) ew[k] = er[k];
                #pragma unroll
                for (int j = 0; j < 3; j++) {
                    const float wv = wd9[i * 3 + j];
                    #pragma unroll
                    for (int p = 0; p < 16; p++) {
                        const int wi = (4 - D) + p + j * D;
                        s16[p] = fmaf(wv, ew[wi >> 2][wi & 3], s16[p]);
                    }
                }
            }
            half8v hv0, hv1;
            #pragma unroll
            for (int p = 0; p < 16; p++) {
                float y = __builtin_amdgcn_logf(fmaxf(s16[p], 1e-38f)) * cs + shift;
                y = fmaxf(0.f, y);
                if (p < 8) hv0[p] = (_Float16)y; else hv1[p - 8] = (_Float16)y;
            }
            // cat layout [b][h][ch][w], ch = d*64+c
            _Float16* cp = &cat[(((size_t)(b * 256 + h0 + dr)) * 256
                                 + (d * C_ + c)) * 256 + (w0 + dq0)];
            *(half8v*)cp = hv0;
            *(half8v*)(cp + 8) = hv1;
        }
    }
}

// Out[64 x 65536] = W[64x256] * Cat per batch, mfma_f32_16x16x32_f16.
// r10-proven front end (ring-3 global_load_lds, counted vmcnt, barrier-free,
// tr-read subtiles, contiguous cat panels).  NEW: LDS-bounce epilogue —
// 2 passes of 32 o-rows; accs -> Lf[32][258] f32 (stride 258: quad offsets
// 8 banks apart -> <=2-way, free), barrier, then each wave stores whole
// rows as f32x4 with 64 lanes covering a contiguous 1 KiB.  16 vector
// stores/thread replace 64 scalar stores (4-B, 256-KiB-strided segments).
__global__ __launch_bounds__(256) void conv_mfma(
    const _Float16* __restrict__ cat, float* __restrict__ out)
{
    __shared__ __align__(16) _Float16 T[3][4][2048];  // 49,152 B
    const int tid = threadIdx.x;
    const int lane = tid & 63, wave = tid >> 6;
    const int m = lane & 15, quad = lane >> 4;
    const int b = blockIdx.y;
    const int h = blockIdx.x;                 // one image row per block
    const int px0 = h * 256;
    const _Float16* catb = cat + ((size_t)(b * 256 + h)) * 256 * 256;  // [ch][w]

    // staging decode (per-lane global src; dest is lane-linear by HW)
    const int c4sel = lane >> 5, p16s = (lane >> 3) & 3;
    const int chl = (lane >> 1) & 3, halfs = lane & 1;
    const int ch_in_q = c4sel * 4 + chl;                 // 0..7
    const int px_s = wave * 64 + p16s * 16 + halfs * 8;  // lane's w base

    const uint t0a = (uint)(uintptr_t)&T[0][0][0];
    const uint trlane = (uint)(quad * 1024 + m * 8);

    f32x4 acc[4][4];
    #pragma unroll
    for (int ot = 0; ot < 4; ot++)
        #pragma unroll
        for (int pt = 0; pt < 4; pt++)
            acc[ot][pt] = (f32x4){0.f, 0.f, 0.f, 0.f};

    half8v a[3][4];

    auto STAGE = [&](int kcs) {
        #pragma unroll
        for (int q = 0; q < 4; ++q) {
            const _Float16* gp = catb + (size_t)(kcs * 32 + q * 8 + ch_in_q) * 256 + px_s;
            __builtin_amdgcn_global_load_lds(
                (gvoid*)gp, (svoid*)&T[kcs % 3][wave][q * 512], 16, 0, 0);
        }
    };
    auto LOADA = [&](int kcs) {
        #pragma unroll
        for (int i = 0; i < 4; ++i)
            a[kcs % 3][i] = *(const half8v*)&g_wh[(i * 16 + m) * 256 + kcs * 32 + quad * 8];
    };

    // prologue (FIFO: S0,A0,S1,A1,S2) — sched_barriers pin issue order
    STAGE(0); __builtin_amdgcn_sched_barrier(0);
    LOADA(0); __builtin_amdgcn_sched_barrier(0);
    STAGE(1); __builtin_amdgcn_sched_barrier(0);
    LOADA(1); __builtin_amdgcn_sched_barrier(0);
    STAGE(2); __builtin_amdgcn_sched_barrier(0);

    #pragma unroll
    for (int kc = 0; kc < 8; ++kc) {
        // counted wait: S(kc)+A(kc) complete, deeper stages stay in flight
        if (kc < 6)       asm volatile("s_waitcnt vmcnt(12)");
        else if (kc == 6) asm volatile("s_waitcnt vmcnt(8)");
        else              asm volatile("s_waitcnt vmcnt(0)");
        __builtin_amdgcn_sched_barrier(0);

        const uint wb = t0a + (uint)(((kc % 3) * 4 + wave) * 4096) + trlane;
        f32x2 trd[4][2];
        #pragma unroll
        for (int pt = 0; pt < 4; ++pt) {
            asm volatile("ds_read_b64_tr_b16 %0, %1"
                         : "=v"(trd[pt][0]) : "v"(wb + pt * 128));
            asm volatile("ds_read_b64_tr_b16 %0, %1"
                         : "=v"(trd[pt][1]) : "v"(wb + 512 + pt * 128));
        }
        asm volatile("s_waitcnt lgkmcnt(0)");
        __builtin_amdgcn_sched_barrier(0);  // rule 18: MFMAs stay below the wait

        #pragma unroll
        for (int pt = 0; pt < 4; ++pt) {
            half4v lo = __builtin_bit_cast(half4v, trd[pt][0]);
            half4v hi = __builtin_bit_cast(half4v, trd[pt][1]);
            half8v bf = __builtin_shufflevector(lo, hi, 0, 1, 2, 3, 4, 5, 6, 7);
            acc[0][pt] = __builtin_amdgcn_mfma_f32_16x16x32_f16(a[kc % 3][0], bf, acc[0][pt], 0, 0, 0);
            acc[1][pt] = __builtin_amdgcn_mfma_f32_16x16x32_f16(a[kc % 3][1], bf, acc[1][pt], 0, 0, 0);
            acc[2][pt] = __builtin_amdgcn_mfma_f32_16x16x32_f16(a[kc % 3][2], bf, acc[2][pt], 0, 0, 0);
            acc[3][pt] = __builtin_amdgcn_mfma_f32_16x16x32_f16(a[kc % 3][3], bf, acc[3][pt], 0, 0, 0);
        }
        __builtin_amdgcn_sched_barrier(0);

        if (kc < 6) { LOADA(kc + 2); }          // A depth 2
        __builtin_amdgcn_sched_barrier(0);
        if (kc < 5) { STAGE(kc + 3); }          // stage depth 3, ring-3
        __builtin_amdgcn_sched_barrier(0);
    }

    // ---- epilogue: vectorized out-store via LDS bounce ----
    // D layout: row(o) = quad*4 + reg, col(px) = m.  Two passes of 32 o.
    // Lf[32][258] f32 = 33,024 B aliases T (pipeline fully drained; Lf
    // spans other waves' ring regions -> __syncthreads guards both sides).
    float* Lf = (float*)&T[0][0][0];
    #pragma unroll
    for (int pass = 0; pass < 2; ++pass) {
        __syncthreads();   // prev pass reads done / all waves' tr-reads done
        #pragma unroll
        for (int oth = 0; oth < 2; ++oth) {
            const int ot = pass * 2 + oth;
            #pragma unroll
            for (int reg = 0; reg < 4; ++reg) {
                const int ol = oth * 16 + quad * 4 + reg;   // 0..31
                #pragma unroll
                for (int pt = 0; pt < 4; ++pt)
                    Lf[ol * 258 + wave * 64 + pt * 16 + m] = acc[ot][pt][reg];
            }
        }
        __syncthreads();   // Lf full
        // 8 sweeps: wave w stores row (sweep*4 + w); 64 lanes x f32x4 = 1 KiB
        #pragma unroll
        for (int sweep = 0; sweep < 8; ++sweep) {
            const int row = sweep * 4 + wave;
            const int o = pass * 32 + row;
            const float sc = g_scale[o], sh = g_shift[o];   // wave-uniform
            const f32x4 rv = *(const f32x4*)&Lf[row * 258 + lane * 4];
            f32x4 y;
            #pragma unroll
            for (int e = 0; e < 4; ++e)
                y[e] = fmaxf(0.f, rv[e] * sc + sh);
            *(f32x4*)(out + ((size_t)(b * 64 + o)) * HW + px0 + lane * 4) = y;
        }
    }
}

extern "C" void kernel_launch(void* const* d_in, const int* in_sizes, int n_in,
                              void* d_out, int out_size, void* d_ws, size_t ws_size,
                              hipStream_t stream)
{
    const float* x   = (const float*)d_in[0];
    const float* we  = (const float*)d_in[1];
    const float* wd  = (const float*)d_in[2];
    const float* bng = (const float*)d_in[3];
    const float* bnb = (const float*)d_in[4];
    const float* bnm = (const float*)d_in[5];
    const float* bnv = (const float*)d_in[6];
    const float* cw  = (const float*)d_in[7];
    const float* fg  = (const float*)d_in[8];
    const float* fb  = (const float*)d_in[9];
    const float* fm  = (const float*)d_in[10];
    const float* fv  = (const float*)d_in[11];
    float* out = (float*)d_out;
    _Float16* cat = (_Float16*)d_ws;  // [b][h][ch][w] fp16 = 128 MiB

    prep<<<64, 256, 0, stream>>>(cw, fg, fb, fm, fv, we, wd, bng, bnb, bnm, bnv);
    morph_all<<<dim3(16, 64, 4), 256, 0, stream>>>(x, cat);
    conv_mfma<<<dim3(256, 4), 256, 0, stream>>>(cat, out);
}

// Round 12
// 235.019 us; speedup vs baseline: 1.2355x; 1.0433x over previous
//
#include <hip/hip_runtime.h>
#include <hip/hip_fp16.h>
#include <math.h>

// MSMOM: multi-scale soft morphological opening + BN/ReLU + 1x1 conv + BN/ReLU
// B=4, C=64, H=W=256, k=3, dilations 1..4, beta=15.
//
// Morph computed in exp2-domain: soft-ero/dil are linear correlations on
// P = 2^{-K x} (K = beta*log2e).  S1 = sum W*P  ->  2^{K e} = 1/S1 (rcp);
// dilation: out = C1*log2( sum Wd * (1/S1) ).  No per-pixel max needed.
//
// History notes (keep):
//  - pk-FMA in morph RETIRED (r5: VGPR 68->172, 30x regression).
//  - conv experiments r4-r11 ALL NEUTRAL: read schedule/fences/staging/
//    layout/write vectorization.  conv left at the r11 form.
//  - morph counters stable 11 rounds: 112us, VALU 61%, HBM 22%, Occ 30%
//    (3 blocks/CU) -> latency/occupancy-bound.  r12: tile 64x64 -> 32x64;
//    LDS 51.7KB -> 29.8KB -> 5 blocks/CU (20 waves).  Also fixes erosion
//    phase imbalance (360 items/2 uneven rounds -> 200 items/1 round) and
//    makes dilation exactly 256 items (8px/thread).

constexpr int C_ = 64, H_ = 256, W_ = 256;
constexpr int HW = H_ * W_;
constexpr float EPSV = 1e-5f;
constexpr float KL2E = 21.64042561333445f;    // beta * log2(e)
constexpr float C1   = 0.046209812037329684f; // ln(2) / beta

typedef __attribute__((ext_vector_type(8))) _Float16 half8v;
typedef __attribute__((ext_vector_type(4))) _Float16 half4v;
typedef __attribute__((ext_vector_type(4))) float f32x4;
typedef __attribute__((ext_vector_type(2))) float f32x2;

typedef const __attribute__((address_space(1))) void gvoid;
typedef __attribute__((address_space(3))) void svoid;

__device__ _Float16 g_wh[64 * 256];  // conv weights fp16, row-major [o][c]
__device__ float g_scale[64];
__device__ float g_shift[64];
__device__ float g_we9e[4 * 64 * 9]; // 2^{K*we}
__device__ float g_wd9e[4 * 64 * 9]; // 2^{K*wd}
__device__ float g_cs[4 * 64];       // C1 * bn_scale  (per d,c)
__device__ float g_sh[4 * 64];       // bn shift       (per d,c)

__global__ __launch_bounds__(256) void prep(
    const float* __restrict__ cw, const float* __restrict__ g,
    const float* __restrict__ bb, const float* __restrict__ bm,
    const float* __restrict__ bv, const float* __restrict__ we,
    const float* __restrict__ wd, const float* __restrict__ bng,
    const float* __restrict__ bnb, const float* __restrict__ bnm,
    const float* __restrict__ bnv)
{
    int i = blockIdx.x * 256 + threadIdx.x;  // 16384 total
    g_wh[i] = (_Float16)cw[i];
    if (i < 64) {
        float s = g[i] * rsqrtf(bv[i] + EPSV);
        g_scale[i] = s;
        g_shift[i] = bb[i] - bm[i] * s;
    }
    if (i < 2304) {
        g_we9e[i] = __builtin_amdgcn_exp2f(KL2E * we[i]);
        g_wd9e[i] = __builtin_amdgcn_exp2f(KL2E * wd[i]);
    }
    if (i < 256) {
        float s = bng[i] * rsqrtf(bnv[i] + EPSV);
        g_cs[i] = C1 * s;
        g_sh[i] = bnb[i] - bnm[i] * s;
    }
}

// One block = one 32x64 tile of one (b,c); all 4 dilations reuse staged P.
// xs: 48 rows x 80 cols, stride 92 (proven bank class).  es: 40 rows x 72
// cols, stride 76.  LDS 29,824 B -> 5 blocks/CU (was 51,712 -> 3).
// Erosion: 5 col-groups x 40 rows = 200 items (single round, balanced).
// Dilation: 32 rows x 8 col-groups of 8 px = 256 items (exactly 1/thread;
// window max index (4-D)+7+2D <= 15 -> 4 aligned f32x4 loads).
__global__ __launch_bounds__(256) void morph_all(
    const float* __restrict__ x, _Float16* __restrict__ cat)
{
    __shared__ __align__(16) float xs[48 * 92];
    __shared__ __align__(16) float es[40 * 76];
    const int tid = threadIdx.x;
    const int tileW = blockIdx.x & 3, tileH = blockIdx.x >> 2;  // 8x4 tiles
    const int c = blockIdx.y, b = blockIdx.z;
    const int h0 = tileH * 32, w0 = tileW * 64;
    const float* xc = x + (b * C_ + c) * HW;

    // staging: P = 2^{-K x}; out-of-image -> 0.  48 rows x 20 float4-groups.
    for (int u = tid; u < 960; u += 256) {
        int r = u / 20, q4 = (u - r * 20) * 4;
        int gh = h0 - 8 + r, gw = w0 - 8 + q4;
        int ch = min(max(gh, 0), 255), cwi = min(max(gw, 0), 252);
        const float4 v = *(const float4*)&xc[ch * W_ + cwi];
        bool ok = ((unsigned)gh < 256u) && ((unsigned)gw < 253u);
        float4 sv;
        sv.x = ok ? __builtin_amdgcn_exp2f(-KL2E * v.x) : 0.f;
        sv.y = ok ? __builtin_amdgcn_exp2f(-KL2E * v.y) : 0.f;
        sv.z = ok ? __builtin_amdgcn_exp2f(-KL2E * v.z) : 0.f;
        sv.w = ok ? __builtin_amdgcn_exp2f(-KL2E * v.w) : 0.f;
        *(float4*)&xs[r * 92 + q4] = sv;
    }

    #pragma unroll
    for (int d = 0; d < 4; d++) {
        const int D = d + 1;
        const int bc = d * C_ + c;

        float w9[9], wd9[9];
        #pragma unroll
        for (int i = 0; i < 9; i++) {
            w9[i]  = g_we9e[bc * 9 + i];
            wd9[i] = g_wd9e[bc * 9 + i];
        }
        const float cs = g_cs[bc];
        const float shift = g_sh[bc];

        __syncthreads();  // staging done / previous dilation reads of es done

        // erosion: 5 col-groups x 40 rows, column-major, 1 item/thread.
        // es row a <-> image row h0-4+a <-> xs row a+4.
        if (tid < 200) {
            const int col = tid / 40;
            const int row = tid - col * 40;
            const int qa0 = col * 16;
            float s16[16];
            #pragma unroll
            for (int p = 0; p < 16; p++) s16[p] = 0.f;
            #pragma unroll
            for (int i = 0; i < 3; i++) {
                const f32x4* xr = (const f32x4*)&xs[(row + 4 + (i - 1) * D) * 92 + qa0];
                f32x4 xw[6];
                #pragma unroll
                for (int k = 0; k < 6; k++) xw[k] = xr[k];
                #pragma unroll
                for (int j = 0; j < 3; j++) {
                    const float wv = w9[i * 3 + j];
                    #pragma unroll
                    for (int p = 0; p < 16; p++) {
                        const int wi = (4 - D) + p + j * D;  // compile-time
                        s16[p] = fmaf(wv, xw[wi >> 2][wi & 3], s16[p]);
                    }
                }
            }
            const bool rowok = (unsigned)(h0 + row - 4) < 256u;
            const int gw0 = w0 + qa0 - 4;
            f32x4 ev[4];
            #pragma unroll
            for (int p = 0; p < 16; p++) {
                float gv = __builtin_amdgcn_rcpf(fmaxf(s16[p], 1e-38f));
                bool ok = rowok && ((unsigned)(gw0 + p) < 256u);
                ev[p >> 2][p & 3] = ok ? gv : 0.f;  // pad: 2^{K*(-BIG)} = 0
            }
            f32x4* ep = (f32x4*)&es[row * 76 + qa0];
            ep[0] = ev[0]; ep[1] = ev[1];
            if (qa0 < 64) { ep[2] = ev[2]; ep[3] = ev[3]; }  // cols 72..79 never read
        }

        __syncthreads();  // es ready

        // dilation: 32 rows x 8 col-groups of 8 px, one group per thread
        {
            const int dr = tid >> 3, dq0 = (tid & 7) * 8;
            float s8[8];
            #pragma unroll
            for (int p = 0; p < 8; p++) s8[p] = 0.f;
            #pragma unroll
            for (int i = 0; i < 3; i++) {
                const f32x4* er = (const f32x4*)&es[(dr + 4 + (i - 1) * D) * 76 + dq0];
                f32x4 ew[4];
                #pragma unroll
                for (int k = 0; k < 4; k++) ew[k] = er[k];
                #pragma unroll
                for (int j = 0; j < 3; j++) {
                    const float wv = wd9[i * 3 + j];
                    #pragma unroll
                    for (int p = 0; p < 8; p++) {
                        const int wi = (4 - D) + p + j * D;  // <= 15
                        s8[p] = fmaf(wv, ew[wi >> 2][wi & 3], s8[p]);
                    }
                }
            }
            half8v hv;
            #pragma unroll
            for (int p = 0; p < 8; p++) {
                float y = __builtin_amdgcn_logf(fmaxf(s8[p], 1e-38f)) * cs + shift;
                hv[p] = (_Float16)fmaxf(0.f, y);
            }
            // cat layout [b][h][ch][w], ch = d*64+c
            _Float16* cp = &cat[(((size_t)(b * 256 + h0 + dr)) * 256
                                 + (d * C_ + c)) * 256 + (w0 + dq0)];
            *(half8v*)cp = hv;
        }
    }
}

// Out[64 x 65536] = W[64x256] * Cat per batch, mfma_f32_16x16x32_f16.
// r11 body unchanged (ring-3 global_load_lds, counted vmcnt, barrier-free,
// tr-read subtiles, contiguous cat panels, LDS-bounce vectorized epilogue).
__global__ __launch_bounds__(256) void conv_mfma(
    const _Float16* __restrict__ cat, float* __restrict__ out)
{
    __shared__ __align__(16) _Float16 T[3][4][2048];  // 49,152 B
    const int tid = threadIdx.x;
    const int lane = tid & 63, wave = tid >> 6;
    const int m = lane & 15, quad = lane >> 4;
    const int b = blockIdx.y;
    const int h = blockIdx.x;                 // one image row per block
    const int px0 = h * 256;
    const _Float16* catb = cat + ((size_t)(b * 256 + h)) * 256 * 256;  // [ch][w]

    // staging decode (per-lane global src; dest is lane-linear by HW)
    const int c4sel = lane >> 5, p16s = (lane >> 3) & 3;
    const int chl = (lane >> 1) & 3, halfs = lane & 1;
    const int ch_in_q = c4sel * 4 + chl;                 // 0..7
    const int px_s = wave * 64 + p16s * 16 + halfs * 8;  // lane's w base

    const uint t0a = (uint)(uintptr_t)&T[0][0][0];
    const uint trlane = (uint)(quad * 1024 + m * 8);

    f32x4 acc[4][4];
    #pragma unroll
    for (int ot = 0; ot < 4; ot++)
        #pragma unroll
        for (int pt = 0; pt < 4; pt++)
            acc[ot][pt] = (f32x4){0.f, 0.f, 0.f, 0.f};

    half8v a[3][4];

    auto STAGE = [&](int kcs) {
        #pragma unroll
        for (int q = 0; q < 4; ++q) {
            const _Float16* gp = catb + (size_t)(kcs * 32 + q * 8 + ch_in_q) * 256 + px_s;
            __builtin_amdgcn_global_load_lds(
                (gvoid*)gp, (svoid*)&T[kcs % 3][wave][q * 512], 16, 0, 0);
        }
    };
    auto LOADA = [&](int kcs) {
        #pragma unroll
        for (int i = 0; i < 4; ++i)
            a[kcs % 3][i] = *(const half8v*)&g_wh[(i * 16 + m) * 256 + kcs * 32 + quad * 8];
    };

    // prologue (FIFO: S0,A0,S1,A1,S2) — sched_barriers pin issue order
    STAGE(0); __builtin_amdgcn_sched_barrier(0);
    LOADA(0); __builtin_amdgcn_sched_barrier(0);
    STAGE(1); __builtin_amdgcn_sched_barrier(0);
    LOADA(1); __builtin_amdgcn_sched_barrier(0);
    STAGE(2); __builtin_amdgcn_sched_barrier(0);

    #pragma unroll
    for (int kc = 0; kc < 8; ++kc) {
        // counted wait: S(kc)+A(kc) complete, deeper stages stay in flight
        if (kc < 6)       asm volatile("s_waitcnt vmcnt(12)");
        else if (kc == 6) asm volatile("s_waitcnt vmcnt(8)");
        else              asm volatile("s_waitcnt vmcnt(0)");
        __builtin_amdgcn_sched_barrier(0);

        const uint wb = t0a + (uint)(((kc % 3) * 4 + wave) * 4096) + trlane;
        f32x2 trd[4][2];
        #pragma unroll
        for (int pt = 0; pt < 4; ++pt) {
            asm volatile("ds_read_b64_tr_b16 %0, %1"
                         : "=v"(trd[pt][0]) : "v"(wb + pt * 128));
            asm volatile("ds_read_b64_tr_b16 %0, %1"
                         : "=v"(trd[pt][1]) : "v"(wb + 512 + pt * 128));
        }
        asm volatile("s_waitcnt lgkmcnt(0)");
        __builtin_amdgcn_sched_barrier(0);  // rule 18: MFMAs stay below the wait

        #pragma unroll
        for (int pt = 0; pt < 4; ++pt) {
            half4v lo = __builtin_bit_cast(half4v, trd[pt][0]);
            half4v hi = __builtin_bit_cast(half4v, trd[pt][1]);
            half8v bf = __builtin_shufflevector(lo, hi, 0, 1, 2, 3, 4, 5, 6, 7);
            acc[0][pt] = __builtin_amdgcn_mfma_f32_16x16x32_f16(a[kc % 3][0], bf, acc[0][pt], 0, 0, 0);
            acc[1][pt] = __builtin_amdgcn_mfma_f32_16x16x32_f16(a[kc % 3][1], bf, acc[1][pt], 0, 0, 0);
            acc[2][pt] = __builtin_amdgcn_mfma_f32_16x16x32_f16(a[kc % 3][2], bf, acc[2][pt], 0, 0, 0);
            acc[3][pt] = __builtin_amdgcn_mfma_f32_16x16x32_f16(a[kc % 3][3], bf, acc[3][pt], 0, 0, 0);
        }
        __builtin_amdgcn_sched_barrier(0);

        if (kc < 6) { LOADA(kc + 2); }          // A depth 2
        __builtin_amdgcn_sched_barrier(0);
        if (kc < 5) { STAGE(kc + 3); }          // stage depth 3, ring-3
        __builtin_amdgcn_sched_barrier(0);
    }

    // ---- epilogue: vectorized out-store via LDS bounce (r11, proven) ----
    float* Lf = (float*)&T[0][0][0];
    #pragma unroll
    for (int pass = 0; pass < 2; ++pass) {
        __syncthreads();
        #pragma unroll
        for (int oth = 0; oth < 2; ++oth) {
            const int ot = pass * 2 + oth;
            #pragma unroll
            for (int reg = 0; reg < 4; ++reg) {
                const int ol = oth * 16 + quad * 4 + reg;   // 0..31
                #pragma unroll
                for (int pt = 0; pt < 4; ++pt)
                    Lf[ol * 258 + wave * 64 + pt * 16 + m] = acc[ot][pt][reg];
            }
        }
        __syncthreads();
        #pragma unroll
        for (int sweep = 0; sweep < 8; ++sweep) {
            const int row = sweep * 4 + wave;
            const int o = pass * 32 + row;
            const float sc = g_scale[o], sh = g_shift[o];
            const f32x4 rv = *(const f32x4*)&Lf[row * 258 + lane * 4];
            f32x4 y;
            #pragma unroll
            for (int e = 0; e < 4; ++e)
                y[e] = fmaxf(0.f, rv[e] * sc + sh);
            *(f32x4*)(out + ((size_t)(b * 64 + o)) * HW + px0 + lane * 4) = y;
        }
    }
}

extern "C" void kernel_launch(void* const* d_in, const int* in_sizes, int n_in,
                              void* d_out, int out_size, void* d_ws, size_t ws_size,
                              hipStream_t stream)
{
    const float* x   = (const float*)d_in[0];
    const float* we  = (const float*)d_in[1];
    const float* wd  = (const float*)d_in[2];
    const float* bng = (const float*)d_in[3];
    const float* bnb = (const float*)d_in[4];
    const float* bnm = (const float*)d_in[5];
    const float* bnv = (const float*)d_in[6];
    const float* cw  = (const float*)d_in[7];
    const float* fg  = (const float*)d_in[8];
    const float* fb  = (const float*)d_in[9];
    const float* fm  = (const float*)d_in[10];
    const float* fv  = (const float*)d_in[11];
    float* out = (float*)d_out;
    _Float16* cat = (_Float16*)d_ws;  // [b][h][ch][w] fp16 = 128 MiB

    prep<<<64, 256, 0, stream>>>(cw, fg, fb, fm, fv, we, wd, bng, bnb, bnm, bnv);
    morph_all<<<dim3(32, 64, 4), 256, 0, stream>>>(x, cat);
    conv_mfma<<<dim3(256, 4), 256, 0, stream>>>(cat, out);
}